// Round 6
// baseline (171.869 us; speedup 1.0000x reference)
//
#include <hip/hip_runtime.h>
#include <hip/hip_bf16.h>

// StructuralAttention v6: occupancy-first. Algebra unchanged:
//   S_eff = X*M*X^T + 1*v^T,  M = Wq^T Wk / sqrt(d);  v = X*(Wk^T bq)/sqrt(d)
//   O     = (P*X)*Wv^T / rowsum(P) + bv
// Pre-kernel -> d_ws: Mt bf16[128][128], w f32[128], Wvb bf16[128][128].
// Main: grid 1024 = 2 blocks per graph (each block: 128 q-rows, 8 waves x 16 rows).
// LDS 65 KB (Xs bf16[256][128] + v f32[256]) -> 2 blocks/CU = 16 waves/CU =
// 4 waves/SIMD (2x R5's TLP). Register budget: one q-tile per wave keeps live set
// ~95 regs < the 128 cap that 4 waves/SIMD requires -> no spills (R3's killer).
// X^T fragments for the T-step are rebuilt in-loop via identity-MFMA transposes.
// One barrier total. Mt/Wvb fragments read from global (L2-resident).

typedef float f32x4 __attribute__((ext_vector_type(4)));
typedef unsigned int u32x2 __attribute__((ext_vector_type(2)));
typedef unsigned int u32x4 __attribute__((ext_vector_type(4)));
typedef short s16x4 __attribute__((ext_vector_type(4)));
typedef short s16x8 __attribute__((ext_vector_type(8)));

#define SCALE 0.088388347648318447f  // 1/sqrt(128)
#define VOFF  65536                  // v f32[256] after Xs
#define LDSSZ 66560
#define WOFF  32768                  // w f32[128] in ws
#define WVB   33280                  // Wvb bf16[128][128] in ws

__device__ __forceinline__ unsigned short bf16s(float a) {
    return __builtin_bit_cast(unsigned short, __float2bfloat16(a));  // RNE
}
__device__ __forceinline__ unsigned bf16pk(float a, float b) {
    return (unsigned)bf16s(a) | ((unsigned)bf16s(b) << 16);
}
__device__ __forceinline__ f32x4 mfma16(u32x2 a, u32x2 b, f32x4 c) {
    return __builtin_amdgcn_mfma_f32_16x16x16bf16_1k(
        __builtin_bit_cast(s16x4, a), __builtin_bit_cast(s16x4, b), c, 0, 0, 0);
}
__device__ __forceinline__ f32x4 mfma32(u32x4 a, u32x4 b, f32x4 c) {
    return __builtin_amdgcn_mfma_f32_16x16x32_bf16(
        __builtin_bit_cast(s16x8, a), __builtin_bit_cast(s16x8, b), c, 0, 0, 0);
}

// Xs: bf16[256][128] row-major + XOR swizzle in 16B units (b128-write safe,
// b64 reads stay 8B-aligned since XORed bits are >= bit4)
__device__ __forceinline__ int ks_off(int row, int d) {
    return (row << 8) + ((d << 1) ^ ((row & 7) << 4));
}

// ---------------- precompute: Mt bf16 + w f32 + Wvb bf16 -> d_ws ----------------
extern "C" __global__ void __launch_bounds__(256)
sattn_pre(const float* __restrict__ Wq, const float* __restrict__ bq,
          const float* __restrict__ Wk, const float* __restrict__ Wv,
          char* __restrict__ wsb)
{
    const int b = blockIdx.x, t = threadIdx.x;
    if (b < 64) {
        const int row = b * 2 + (t >> 7);   // Mt row = "k-side" feature
        const int a   = t & 127;
        float acc = 0.f;
#pragma unroll 4
        for (int o = 0; o < 128; ++o)
            acc += Wq[o * 128 + a] * Wk[o * 128 + row];
        *(unsigned short*)(wsb + (row << 8) + (a << 1)) = bf16s(acc * SCALE);
    } else if (b == 64) {
        if (t < 128) {
            float acc = 0.f;
#pragma unroll 4
            for (int o = 0; o < 128; ++o)
                acc += bq[o] * Wk[o * 128 + t];
            *(float*)(wsb + WOFF + 4 * t) = acc * SCALE;
        }
    } else {
        const int row = (b - 65) * 2 + (t >> 7);
        const int col = t & 127;
        *(unsigned short*)(wsb + WVB + (row << 8) + (col << 1)) =
            bf16s(Wv[row * 128 + col]);
    }
}

// ---------------- main fused kernel: 2 blocks (8 waves each) per graph ----------
extern "C" __global__ void __launch_bounds__(512, 4)
sattn(const float* __restrict__ x, const float* __restrict__ bv,
      const char* __restrict__ wsb, float* __restrict__ out)
{
    extern __shared__ char sm[];
    const int t    = threadIdx.x;
    const int lane = t & 63;
    const int w    = t >> 6;                 // wave 0..7
    const int h    = lane & 15;
    const int g    = lane >> 4;
    const int gid  = blockIdx.x >> 1;        // graph id
    const int half = blockIdx.x & 1;         // which 128-row q-half
    const int R0   = gid << 8;
    const int q0   = (half << 7) + (w << 4); // wave's q-tile base within graph
    const f32x4 Z  = {0.f, 0.f, 0.f, 0.f};

    // ---- stage all 256 X rows -> Xs (bf16, swizzled) + v = X*w ----
    {
        const int row = t >> 1, ch = (t & 1) << 6;   // thread: row, 64-col half
        const float* xr = x + (size_t)(R0 + row) * 128 + ch;
        const float* wv = (const float*)(wsb + WOFF) + ch;
        float vacc = 0.f;
#pragma unroll
        for (int m = 0; m < 4; ++m) {
            f32x4 a0 = *(const f32x4*)(xr + 16 * m);
            f32x4 a1 = *(const f32x4*)(xr + 16 * m + 4);
            f32x4 a2 = *(const f32x4*)(xr + 16 * m + 8);
            f32x4 a3 = *(const f32x4*)(xr + 16 * m + 12);
            f32x4 w0 = *(const f32x4*)(wv + 16 * m);
            f32x4 w1 = *(const f32x4*)(wv + 16 * m + 4);
            f32x4 w2 = *(const f32x4*)(wv + 16 * m + 8);
            f32x4 w3 = *(const f32x4*)(wv + 16 * m + 12);
            vacc += a0.x * w0.x + a0.y * w0.y + a0.z * w0.z + a0.w * w0.w
                  + a1.x * w1.x + a1.y * w1.y + a1.z * w1.z + a1.w * w1.w
                  + a2.x * w2.x + a2.y * w2.y + a2.z * w2.z + a2.w * w2.w
                  + a3.x * w3.x + a3.y * w3.y + a3.z * w3.z + a3.w * w3.w;
            u32x4 lo = (u32x4){ bf16pk(a0.x, a0.y), bf16pk(a0.z, a0.w),
                                bf16pk(a1.x, a1.y), bf16pk(a1.z, a1.w) };
            u32x4 hi = (u32x4){ bf16pk(a2.x, a2.y), bf16pk(a2.z, a2.w),
                                bf16pk(a3.x, a3.y), bf16pk(a3.z, a3.w) };
            *(u32x4*)(sm + ks_off(row, ch + 16 * m))     = lo;
            *(u32x4*)(sm + ks_off(row, ch + 16 * m + 8)) = hi;
        }
        vacc += __shfl_xor(vacc, 1);
        if ((t & 1) == 0) *(float*)(sm + VOFF + row * 4) = vacc;
    }
    __syncthreads();   // Xs + v visible (the only barrier)

    // ---- Y fragments for own q-tile: yf[jt] = Y[q=q0+h][b=16jt+4g+r] ----
    u32x2 bx[8];       // own-row X fragments (b-slots), re-read from LDS
#pragma unroll
    for (int c = 0; c < 8; ++c)
        bx[c] = *(const u32x2*)(sm + ks_off(q0 + h, 16 * c + 4 * g));
    u32x2 yf[8];
#pragma unroll
    for (int jt = 0; jt < 8; ++jt) {
        f32x4 a = Z;
#pragma unroll
        for (int c2 = 0; c2 < 4; ++c2) {
            const char* mp = wsb + ((h + 16 * jt) << 8) + ((32 * c2 + 4 * g) << 1);
            u32x2 mlo = *(const u32x2*)mp;
            u32x2 mhi = *(const u32x2*)(mp + 32);
            u32x4 A = (u32x4){ mlo.x, mlo.y, mhi.x, mhi.y };
            u32x4 B = (u32x4){ bx[2 * c2].x, bx[2 * c2].y,
                               bx[2 * c2 + 1].x, bx[2 * c2 + 1].y };
            a = mfma32(A, B, a);
        }
        yf[jt] = (u32x2){ bf16pk(a.x, a.y), bf16pk(a.z, a.w) };
    }

    // identity B-fragment for transpose-MFMAs: B[c=4g+i][col=h] = (4g+i==h)
    const int ii = h - 4 * g;
    u32x2 idf;
    idf.x = (ii == 0 ? 0x3F80u : 0u) | (ii == 1 ? (0x3F80u << 16) : 0u);
    idf.y = (ii == 2 ? 0x3F80u : 0u) | (ii == 3 ? (0x3F80u << 16) : 0u);

    // ---- main loop: S^T = Xs*yf ; P = exp(S+v); T += P * X (X^T rebuilt in-loop) --
    f32x4 Tacc[8];     // Tacc[jt]: lane h reg r = T[q=4g+r][d=16jt+h]
#pragma unroll
    for (int jt = 0; jt < 8; ++jt) Tacc[jt] = Z;
    float ls = 0.f;

#pragma unroll 1
    for (int kc2 = 0; kc2 < 8; ++kc2) {
        u32x2 pk2[2];
#pragma unroll
        for (int kk = 0; kk < 2; ++kk) {
            const int kc = 2 * kc2 + kk;
            f32x4 a = Z;
#pragma unroll
            for (int c2 = 0; c2 < 4; ++c2) {
                u32x2 xlo = *(const u32x2*)(sm + ks_off(16 * kc + h, 32 * c2 + 4 * g));
                u32x2 xhi = *(const u32x2*)(sm + ks_off(16 * kc + h, 32 * c2 + 16 + 4 * g));
                u32x4 A = (u32x4){ xlo.x, xlo.y, xhi.x, xhi.y };
                u32x4 B = (u32x4){ yf[2 * c2].x, yf[2 * c2].y,
                                   yf[2 * c2 + 1].x, yf[2 * c2 + 1].y };
                a = mfma32(A, B, a);   // lane h reg r = S[k=16kc+4g+r][q=q0+h]
            }
            f32x4 vv = *(const f32x4*)(sm + VOFF + (16 * kc + 4 * g) * 4);
            float e0 = __expf(a.x + vv.x), e1 = __expf(a.y + vv.y);
            float e2 = __expf(a.z + vv.z), e3 = __expf(a.w + vv.w);
            ls += e0 + e1 + e2 + e3;
            pk2[kk] = (u32x2){ bf16pk(e0, e1), bf16pk(e2, e3) };
        }
        u32x4 pa = (u32x4){ pk2[0].x, pk2[0].y, pk2[1].x, pk2[1].y };
#pragma unroll
        for (int jt = 0; jt < 8; ++jt) {
            // X^T B-fragments via identity-MFMA transpose of row-major Xs reads
            u32x2 ra = *(const u32x2*)(sm + ks_off(32 * kc2 + h,      16 * jt + 4 * g));
            u32x2 rb = *(const u32x2*)(sm + ks_off(32 * kc2 + 16 + h, 16 * jt + 4 * g));
            f32x4 ta = mfma16(ra, idf, Z);   // lane h reg r = X[32kc2+4g+r][16jt+h]
            f32x4 tb = mfma16(rb, idf, Z);   // ... rows +16
            u32x4 tB = (u32x4){ bf16pk(ta.x, ta.y), bf16pk(ta.z, ta.w),
                                bf16pk(tb.x, tb.y), bf16pk(tb.z, tb.w) };
            Tacc[jt] = mfma32(pa, tB, Tacc[jt]);
        }
    }
    ls += __shfl_xor(ls, 16); ls += __shfl_xor(ls, 32);
    const float li = 1.0f / ls;   // inverse row-sum for q = q0 + h

    // ---- transpose-pack Tacc -> T^T B-fragments (register-only) ----
    u32x4 tBO[4];
#pragma unroll
    for (int c2 = 0; c2 < 4; ++c2) {
        u32x2 p0 = (u32x2){ bf16pk(Tacc[2 * c2].x, Tacc[2 * c2].y),
                            bf16pk(Tacc[2 * c2].z, Tacc[2 * c2].w) };
        u32x2 p1 = (u32x2){ bf16pk(Tacc[2 * c2 + 1].x, Tacc[2 * c2 + 1].y),
                            bf16pk(Tacc[2 * c2 + 1].z, Tacc[2 * c2 + 1].w) };
        f32x4 d0 = mfma16(p0, idf, Z);   // lane h reg r = T[q=q0+h][d=32c2+4g+r]
        f32x4 d1 = mfma16(p1, idf, Z);   // ... d=32c2+16+4g+r
        tBO[c2] = (u32x4){ bf16pk(d0.x, d0.y), bf16pk(d0.z, d0.w),
                           bf16pk(d1.x, d1.y), bf16pk(d1.z, d1.w) };
    }

    // ---- O^T = Wvb * T^T (Wvb from global/L2); normalize + bias; f32x4 stores ----
#pragma unroll
    for (int ot = 0; ot < 8; ++ot) {
        f32x4 o = Z;
#pragma unroll
        for (int c2 = 0; c2 < 4; ++c2) {
            const char* wp = wsb + WVB + ((h + 16 * ot) << 8) + ((32 * c2 + 4 * g) << 1);
            u32x2 wlo = *(const u32x2*)wp;
            u32x2 whi = *(const u32x2*)(wp + 32);
            u32x4 A = (u32x4){ wlo.x, wlo.y, whi.x, whi.y };
            o = mfma32(A, tBO[c2], o);   // lane h reg r = O[q=q0+h][16ot+4g+r]
        }
        f32x4 bvv = *(const f32x4*)(bv + 16 * ot + 4 * g);
        f32x4 r;
#pragma unroll
        for (int j = 0; j < 4; ++j) r[j] = o[j] * li + bvv[j];
        *(f32x4*)(out + (size_t)(R0 + q0 + h) * 128 + 16 * ot + 4 * g) = r;
    }
}

extern "C" void kernel_launch(void* const* d_in, const int* in_sizes, int n_in,
                              void* d_out, int out_size, void* d_ws, size_t ws_size,
                              hipStream_t stream) {
    const float* x  = (const float*)d_in[0];
    const float* Wq = (const float*)d_in[2];
    const float* bq = (const float*)d_in[3];
    const float* Wk = (const float*)d_in[4];
    const float* Wv = (const float*)d_in[6];
    const float* bv = (const float*)d_in[7];
    float* out = (float*)d_out;
    char* wsb = (char*)d_ws;

    hipFuncSetAttribute((const void*)sattn,
                        hipFuncAttributeMaxDynamicSharedMemorySize, LDSSZ);

    sattn_pre<<<dim3(129), dim3(256), 0, stream>>>(Wq, bq, Wk, Wv, wsb);
    sattn<<<dim3(1024), dim3(512), LDSSZ, stream>>>(x, bv, wsb, out);
}

// Round 7
// 113.120 us; speedup vs baseline: 1.5193x; 1.5193x over previous
//
#include <hip/hip_runtime.h>
#include <hip/hip_bf16.h>

// StructuralAttention v7: short-chain inner loop.
//   S_eff = X*M*X^T + 1*v^T,  M = Wq^T Wk / sqrt(d);  v = X*(Wk^T bq)/sqrt(d)
//   Vt    = (X*Wv^T)^T  (no bias), built in prologue -> LDS
//   O     = P*Vt^T / rowsum(P) + bv
// Insight: the S^T-step MFMA output (lane h reg r = S[k=4g+r][q=h]) is, after exp,
// EXACTLY the B-operand fragment P[q=h][k-slots] for O^T += mfma32(A=Vt-rows, B=P).
// -> no transpose MFMAs anywhere in the main loop, and O^T is store-ready.
// Main: 512 thr (8 waves), 1 block/graph, 2 q-tiles/wave (shared A-frags).
// __launch_bounds__(512,2) = 256 regs/wave (the only regime that hasn't
// register-starved: R2-R4/R6 all died of 128-cap starvation or spills).
// LDS 129 KB: Xs bf16[256][128] + Vt bf16[128][256] + v f32[256].

typedef float f32x4 __attribute__((ext_vector_type(4)));
typedef unsigned int u32x2 __attribute__((ext_vector_type(2)));
typedef unsigned int u32x4 __attribute__((ext_vector_type(4)));
typedef short s16x8 __attribute__((ext_vector_type(8)));

#define SCALE 0.088388347648318447f  // 1/sqrt(128)
#define VT0   65536                  // Vt bf16[128][256]
#define VOFF  131072                 // v f32[256]
#define LDSSZ 132096
#define WOFF  32768                  // w f32[128] in ws
#define WVB   33280                  // Wvb bf16[128][128] in ws

__device__ __forceinline__ unsigned short bf16s(float a) {
    return __builtin_bit_cast(unsigned short, __float2bfloat16(a));  // RNE
}
__device__ __forceinline__ unsigned bf16pk(float a, float b) {
    return (unsigned)bf16s(a) | ((unsigned)bf16s(b) << 16);
}
__device__ __forceinline__ f32x4 mfma32(u32x4 a, u32x4 b, f32x4 c) {
    return __builtin_amdgcn_mfma_f32_16x16x32_bf16(
        __builtin_bit_cast(s16x8, a), __builtin_bit_cast(s16x8, b), c, 0, 0, 0);
}

// Xs: bf16[256][128] row-major; XOR spreads 16 distinct rows across 16 8B slots
__device__ __forceinline__ int ks_off(int row, int d) {
    return (row << 8) + ((d << 1) ^ ((row & 15) << 3));
}
// Vt: bf16[128][256] row-major (row = output feature o, col = node k)
__device__ __forceinline__ int vt_off(int o, int k) {
    return VT0 + (o << 9) + ((k << 1) ^ ((o & 15) << 3));
}

// ---------------- precompute: Mt bf16 + w f32 + Wvb bf16 -> d_ws ----------------
extern "C" __global__ void __launch_bounds__(256)
sattn_pre(const float* __restrict__ Wq, const float* __restrict__ bq,
          const float* __restrict__ Wk, const float* __restrict__ Wv,
          char* __restrict__ wsb)
{
    const int b = blockIdx.x, t = threadIdx.x;
    if (b < 64) {
        const int row = b * 2 + (t >> 7);   // Mt row = "k-side" feature
        const int a   = t & 127;
        float acc = 0.f;
#pragma unroll 4
        for (int o = 0; o < 128; ++o)
            acc += Wq[o * 128 + a] * Wk[o * 128 + row];
        *(unsigned short*)(wsb + (row << 8) + (a << 1)) = bf16s(acc * SCALE);
    } else if (b == 64) {
        if (t < 128) {
            float acc = 0.f;
#pragma unroll 4
            for (int o = 0; o < 128; ++o)
                acc += bq[o] * Wk[o * 128 + t];
            *(float*)(wsb + WOFF + 4 * t) = acc * SCALE;
        }
    } else {
        const int row = (b - 65) * 2 + (t >> 7);
        const int col = t & 127;
        *(unsigned short*)(wsb + WVB + (row << 8) + (col << 1)) =
            bf16s(Wv[row * 128 + col]);
    }
}

// ---------------- main fused kernel: 1 block (8 waves) per graph ----------------
extern "C" __global__ void __launch_bounds__(512, 2)
sattn(const float* __restrict__ x, const float* __restrict__ bv,
      const char* __restrict__ wsb, float* __restrict__ out)
{
    extern __shared__ char sm[];
    const int t    = threadIdx.x;
    const int lane = t & 63;
    const int w    = t >> 6;        // wave 0..7
    const int h    = lane & 15;
    const int g    = lane >> 4;
    const int R0   = blockIdx.x << 8;
    const int q0   = w << 5;        // wave's 32-q-row slab (two 16-row tiles)
    const f32x4 Z  = {0.f, 0.f, 0.f, 0.f};

    // ---- phase A: stage all 256 X rows -> Xs (bf16) + v = X*w ----
    {
        const int row = t >> 1, ch = (t & 1) << 6;   // 2 threads/row, 64-col halves
        const float* xr = x + (size_t)(R0 + row) * 128 + ch;
        const float* wv = (const float*)(wsb + WOFF) + ch;
        float vacc = 0.f;
#pragma unroll
        for (int j = 0; j < 16; ++j) {
            f32x4 a = *(const f32x4*)(xr + 4 * j);
            f32x4 wj = *(const f32x4*)(wv + 4 * j);
            vacc += a.x * wj.x + a.y * wj.y + a.z * wj.z + a.w * wj.w;
            *(u32x2*)(sm + ks_off(row, ch + 4 * j)) =
                (u32x2){ bf16pk(a.x, a.y), bf16pk(a.z, a.w) };
        }
        vacc += __shfl_xor(vacc, 1);
        if ((t & 1) == 0) *(float*)(sm + VOFF + row * 4) = vacc;
    }
    __syncthreads();   // Xs + v visible

    // ---- phase B: Vt = (X*Wv^T)^T. Wave w: k-rows 32w..32w+31, all 128 o. ----
    // mfma32(A=X-row-frags, B=Wvb-row-frags) -> lane h reg r = V[k=32w+16kt+4g+r][o=16ot+h]
    // regs r=0..3 are 4 CONTIGUOUS k -> pack to u32x2, b64-write into Vt[o][k]. No transpose.
    {
        u32x2 xk[2][8];
#pragma unroll
        for (int kt = 0; kt < 2; ++kt)
#pragma unroll
            for (int c = 0; c < 8; ++c)
                xk[kt][c] = *(const u32x2*)(sm + ks_off(32 * w + 16 * kt + h, 16 * c + 4 * g));
#pragma unroll
        for (int ot = 0; ot < 8; ++ot) {
            f32x4 D0 = Z, D1 = Z;
#pragma unroll
            for (int c2 = 0; c2 < 4; ++c2) {
                const char* wp = wsb + WVB + ((16 * ot + h) << 8) + ((32 * c2 + 4 * g) << 1);
                u32x2 wlo = *(const u32x2*)wp;
                u32x2 whi = *(const u32x2*)(wp + 32);
                u32x4 B = (u32x4){ wlo.x, wlo.y, whi.x, whi.y };
                u32x4 A0 = (u32x4){ xk[0][2 * c2].x, xk[0][2 * c2].y,
                                    xk[0][2 * c2 + 1].x, xk[0][2 * c2 + 1].y };
                u32x4 A1 = (u32x4){ xk[1][2 * c2].x, xk[1][2 * c2].y,
                                    xk[1][2 * c2 + 1].x, xk[1][2 * c2 + 1].y };
                D0 = mfma32(A0, B, D0);
                D1 = mfma32(A1, B, D1);
            }
            *(u32x2*)(sm + vt_off(16 * ot + h, 32 * w + 4 * g)) =
                (u32x2){ bf16pk(D0.x, D0.y), bf16pk(D0.z, D0.w) };
            *(u32x2*)(sm + vt_off(16 * ot + h, 32 * w + 16 + 4 * g)) =
                (u32x2){ bf16pk(D1.x, D1.y), bf16pk(D1.z, D1.w) };
        }
    }

    // ---- phase C: Y-frags for both q-tiles (Mt from global/L2) ----
    u32x2 yf[8][2];   // yf[jt][qt]: lane h = Y[q=q0+16qt+h][b=16jt+4g+i]
    {
        u32x2 bx[2][8];
#pragma unroll
        for (int qt = 0; qt < 2; ++qt)
#pragma unroll
            for (int c = 0; c < 8; ++c)
                bx[qt][c] = *(const u32x2*)(sm + ks_off(q0 + 16 * qt + h, 16 * c + 4 * g));
#pragma unroll
        for (int jt = 0; jt < 8; ++jt) {
            f32x4 a0 = Z, a1 = Z;
#pragma unroll
            for (int c2 = 0; c2 < 4; ++c2) {
                const char* mp = wsb + ((h + 16 * jt) << 8) + ((32 * c2 + 4 * g) << 1);
                u32x2 mlo = *(const u32x2*)mp;
                u32x2 mhi = *(const u32x2*)(mp + 32);
                u32x4 A = (u32x4){ mlo.x, mlo.y, mhi.x, mhi.y };
                u32x4 B0 = (u32x4){ bx[0][2 * c2].x, bx[0][2 * c2].y,
                                    bx[0][2 * c2 + 1].x, bx[0][2 * c2 + 1].y };
                u32x4 B1 = (u32x4){ bx[1][2 * c2].x, bx[1][2 * c2].y,
                                    bx[1][2 * c2 + 1].x, bx[1][2 * c2 + 1].y };
                a0 = mfma32(A, B0, a0);
                a1 = mfma32(A, B1, a1);
            }
            yf[jt][0] = (u32x2){ bf16pk(a0.x, a0.y), bf16pk(a0.z, a0.w) };
            yf[jt][1] = (u32x2){ bf16pk(a1.x, a1.y), bf16pk(a1.z, a1.w) };
        }
    }
    __syncthreads();   // Vt visible

    // ---- main loop: S^T = Xs*yf ; P = exp(S+v) (B-frag-ready!) ; O^T += Vt*P ----
    f32x4 Oacc[8][2];  // Oacc[ot][qt]: lane h reg r = O^T[o=16ot+4g+r][q=q0+16qt+h]
#pragma unroll
    for (int ot = 0; ot < 8; ++ot) { Oacc[ot][0] = Z; Oacc[ot][1] = Z; }
    float ls0 = 0.f, ls1 = 0.f;

#pragma unroll 2
    for (int kc2 = 0; kc2 < 8; ++kc2) {
        u32x2 pk0[2], pk1[2];
#pragma unroll
        for (int kk = 0; kk < 2; ++kk) {
            const int kc = 2 * kc2 + kk;
            f32x4 a0 = Z, a1 = Z;
#pragma unroll
            for (int c2 = 0; c2 < 4; ++c2) {
                u32x2 xlo = *(const u32x2*)(sm + ks_off(16 * kc + h, 32 * c2 + 4 * g));
                u32x2 xhi = *(const u32x2*)(sm + ks_off(16 * kc + h, 32 * c2 + 16 + 4 * g));
                u32x4 A = (u32x4){ xlo.x, xlo.y, xhi.x, xhi.y };
                u32x4 B0 = (u32x4){ yf[2 * c2][0].x, yf[2 * c2][0].y,
                                    yf[2 * c2 + 1][0].x, yf[2 * c2 + 1][0].y };
                u32x4 B1 = (u32x4){ yf[2 * c2][1].x, yf[2 * c2][1].y,
                                    yf[2 * c2 + 1][1].x, yf[2 * c2 + 1][1].y };
                a0 = mfma32(A, B0, a0);   // lane h reg r = S[k=16kc+4g+r][q=q0+h]
                a1 = mfma32(A, B1, a1);   // ... q=q0+16+h
            }
            f32x4 vv = *(const f32x4*)(sm + VOFF + (16 * kc + 4 * g) * 4);
            float e0 = __expf(a0.x + vv.x), e1 = __expf(a0.y + vv.y);
            float e2 = __expf(a0.z + vv.z), e3 = __expf(a0.w + vv.w);
            float f0 = __expf(a1.x + vv.x), f1 = __expf(a1.y + vv.y);
            float f2 = __expf(a1.z + vv.z), f3 = __expf(a1.w + vv.w);
            ls0 += e0 + e1 + e2 + e3;
            ls1 += f0 + f1 + f2 + f3;
            pk0[kk] = (u32x2){ bf16pk(e0, e1), bf16pk(e2, e3) };
            pk1[kk] = (u32x2){ bf16pk(f0, f1), bf16pk(f2, f3) };
        }
        // P-fragments ARE B-operands: pa[qt] = P[q][k-slots 32kc2+4g+i, +16]
        u32x4 pa0 = (u32x4){ pk0[0].x, pk0[0].y, pk0[1].x, pk0[1].y };
        u32x4 pa1 = (u32x4){ pk1[0].x, pk1[0].y, pk1[1].x, pk1[1].y };
#pragma unroll
        for (int ot = 0; ot < 8; ++ot) {
            u32x2 vlo = *(const u32x2*)(sm + vt_off(16 * ot + h, 32 * kc2 + 4 * g));
            u32x2 vhi = *(const u32x2*)(sm + vt_off(16 * ot + h, 32 * kc2 + 16 + 4 * g));
            u32x4 A = (u32x4){ vlo.x, vlo.y, vhi.x, vhi.y };
            Oacc[ot][0] = mfma32(A, pa0, Oacc[ot][0]);
            Oacc[ot][1] = mfma32(A, pa1, Oacc[ot][1]);
        }
    }
    ls0 += __shfl_xor(ls0, 16); ls0 += __shfl_xor(ls0, 32);
    ls1 += __shfl_xor(ls1, 16); ls1 += __shfl_xor(ls1, 32);
    const float li0 = 1.0f / ls0;   // for q = q0 + h
    const float li1 = 1.0f / ls1;   // for q = q0 + 16 + h

    // ---- epilogue: O^T is store-ready (regs r = 4 contiguous o-cols) ----
#pragma unroll
    for (int ot = 0; ot < 8; ++ot) {
        f32x4 bvv = *(const f32x4*)(bv + 16 * ot + 4 * g);
        f32x4 r0, r1;
#pragma unroll
        for (int j = 0; j < 4; ++j) {
            r0[j] = Oacc[ot][0][j] * li0 + bvv[j];
            r1[j] = Oacc[ot][1][j] * li1 + bvv[j];
        }
        *(f32x4*)(out + (size_t)(R0 + q0 + h) * 128 + 16 * ot + 4 * g)      = r0;
        *(f32x4*)(out + (size_t)(R0 + q0 + 16 + h) * 128 + 16 * ot + 4 * g) = r1;
    }
}

extern "C" void kernel_launch(void* const* d_in, const int* in_sizes, int n_in,
                              void* d_out, int out_size, void* d_ws, size_t ws_size,
                              hipStream_t stream) {
    const float* x  = (const float*)d_in[0];
    const float* Wq = (const float*)d_in[2];
    const float* bq = (const float*)d_in[3];
    const float* Wk = (const float*)d_in[4];
    const float* Wv = (const float*)d_in[6];
    const float* bv = (const float*)d_in[7];
    float* out = (float*)d_out;
    char* wsb = (char*)d_ws;

    hipFuncSetAttribute((const void*)sattn,
                        hipFuncAttributeMaxDynamicSharedMemorySize, LDSSZ);

    sattn_pre<<<dim3(129), dim3(256), 0, stream>>>(Wq, bq, Wk, Wv, wsb);
    sattn<<<dim3(512), dim3(512), LDSSZ, stream>>>(x, bv, wsb, out);
}

// Round 8
// 112.717 us; speedup vs baseline: 1.5248x; 1.0036x over previous
//
#include <hip/hip_runtime.h>
#include <hip/hip_bf16.h>

// StructuralAttention v8 = v7 compute + MLP-fixed staging.
// Diagnosis (R1-R7): every variant was latency-bound on the x->LDS staging phase
// (loads sunk to uses => ~2KB in flight/CU => ~900 GB/s chip). Fix: issue ALL
// 16 dwordx4 loads into registers, sched_barrier, then convert+write. Phase A
// becomes BW-bound (~131 KB in flight/CU).
//   S_eff = X*M*X^T + 1*v^T,  M = Wq^T Wk / sqrt(d);  v = X*(Wk^T bq)/sqrt(d)
//   Vt    = (X*Wv^T)^T (prologue GEMM, transpose-free store into LDS)
//   O     = P*Vt^T / rowsum(P) + bv
// Main: 512 thr (8 waves), 1 block/graph, 2 q-tiles/wave, (512,2) = 256 regs/wave.
// LDS 129 KB: Xs bf16[256][128] + Vt bf16[128][256] + v f32[256].

typedef float f32x4 __attribute__((ext_vector_type(4)));
typedef unsigned int u32x2 __attribute__((ext_vector_type(2)));
typedef unsigned int u32x4 __attribute__((ext_vector_type(4)));
typedef short s16x8 __attribute__((ext_vector_type(8)));

#define SCALE 0.088388347648318447f  // 1/sqrt(128)
#define VT0   65536                  // Vt bf16[128][256]
#define VOFF  131072                 // v f32[256]
#define LDSSZ 132096
#define WOFF  32768                  // w f32[128] in ws
#define WVB   33280                  // Wvb bf16[128][128] in ws

__device__ __forceinline__ unsigned short bf16s(float a) {
    return __builtin_bit_cast(unsigned short, __float2bfloat16(a));  // RNE
}
__device__ __forceinline__ unsigned bf16pk(float a, float b) {
    return (unsigned)bf16s(a) | ((unsigned)bf16s(b) << 16);
}
__device__ __forceinline__ f32x4 mfma32(u32x4 a, u32x4 b, f32x4 c) {
    return __builtin_amdgcn_mfma_f32_16x16x32_bf16(
        __builtin_bit_cast(s16x8, a), __builtin_bit_cast(s16x8, b), c, 0, 0, 0);
}

// Xs: bf16[256][128] row-major; XOR spreads 16 distinct rows across 16 8B slots
__device__ __forceinline__ int ks_off(int row, int d) {
    return (row << 8) + ((d << 1) ^ ((row & 15) << 3));
}
// Vt: bf16[128][256] row-major (row = output feature o, col = node k)
__device__ __forceinline__ int vt_off(int o, int k) {
    return VT0 + (o << 9) + ((k << 1) ^ ((o & 15) << 3));
}

// ---------------- precompute: Mt bf16 + w f32 + Wvb bf16 -> d_ws ----------------
extern "C" __global__ void __launch_bounds__(256)
sattn_pre(const float* __restrict__ Wq, const float* __restrict__ bq,
          const float* __restrict__ Wk, const float* __restrict__ Wv,
          char* __restrict__ wsb)
{
    const int b = blockIdx.x, t = threadIdx.x;
    if (b < 64) {
        const int row = b * 2 + (t >> 7);   // Mt row = "k-side" feature
        const int a   = t & 127;
        float acc = 0.f;
#pragma unroll 4
        for (int o = 0; o < 128; ++o)
            acc += Wq[o * 128 + a] * Wk[o * 128 + row];
        *(unsigned short*)(wsb + (row << 8) + (a << 1)) = bf16s(acc * SCALE);
    } else if (b == 64) {
        if (t < 128) {
            float acc = 0.f;
#pragma unroll 4
            for (int o = 0; o < 128; ++o)
                acc += bq[o] * Wk[o * 128 + t];
            *(float*)(wsb + WOFF + 4 * t) = acc * SCALE;
        }
    } else {
        const int row = (b - 65) * 2 + (t >> 7);
        const int col = t & 127;
        *(unsigned short*)(wsb + WVB + (row << 8) + (col << 1)) =
            bf16s(Wv[row * 128 + col]);
    }
}

// ---------------- main fused kernel: 1 block (8 waves) per graph ----------------
extern "C" __global__ void __launch_bounds__(512, 2)
sattn(const float* __restrict__ x, const float* __restrict__ bv,
      const char* __restrict__ wsb, float* __restrict__ out)
{
    extern __shared__ char sm[];
    const int t    = threadIdx.x;
    const int lane = t & 63;
    const int w    = t >> 6;        // wave 0..7
    const int h    = lane & 15;
    const int g    = lane >> 4;
    const int R0   = blockIdx.x << 8;
    const int q0   = w << 5;        // wave's 32-q-row slab (two 16-row tiles)
    const f32x4 Z  = {0.f, 0.f, 0.f, 0.f};

    // ---- phase A: stage all 256 X rows -> Xs (bf16) + v = X*w ----
    // CRITICAL: issue all 16 global loads BEFORE any consumer (MLP fix).
    {
        const int row = t >> 1, ch = (t & 1) << 6;   // 2 threads/row, 64-col halves
        const float* xr = x + (size_t)(R0 + row) * 128 + ch;
        const float* wv = (const float*)(wsb + WOFF) + ch;
        f32x4 xa[16];
#pragma unroll
        for (int j = 0; j < 16; ++j) xa[j] = *(const f32x4*)(xr + 4 * j);
        __builtin_amdgcn_sched_barrier(0);   // keep loads issued ahead of uses
        float vacc = 0.f;
#pragma unroll
        for (int j = 0; j < 16; ++j) {
            f32x4 wj = *(const f32x4*)(wv + 4 * j);
            vacc += xa[j].x * wj.x + xa[j].y * wj.y + xa[j].z * wj.z + xa[j].w * wj.w;
            *(u32x2*)(sm + ks_off(row, ch + 4 * j)) =
                (u32x2){ bf16pk(xa[j].x, xa[j].y), bf16pk(xa[j].z, xa[j].w) };
        }
        vacc += __shfl_xor(vacc, 1);
        if ((t & 1) == 0) *(float*)(sm + VOFF + row * 4) = vacc;
    }
    __syncthreads();   // Xs + v visible

    // ---- phase B: Vt = (X*Wv^T)^T. Wave w: k-rows 32w..32w+31, all 128 o. ----
    // lane h reg r = V[k=32w+16kt+4g+r][o=16ot+h]: 4 contiguous k -> b64 Vt write.
    {
        u32x2 xk[2][8];
#pragma unroll
        for (int kt = 0; kt < 2; ++kt)
#pragma unroll
            for (int c = 0; c < 8; ++c)
                xk[kt][c] = *(const u32x2*)(sm + ks_off(32 * w + 16 * kt + h, 16 * c + 4 * g));
#pragma unroll
        for (int ot = 0; ot < 8; ++ot) {
            f32x4 D0 = Z, D1 = Z;
#pragma unroll
            for (int c2 = 0; c2 < 4; ++c2) {
                const char* wp = wsb + WVB + ((16 * ot + h) << 8) + ((32 * c2 + 4 * g) << 1);
                u32x2 wlo = *(const u32x2*)wp;
                u32x2 whi = *(const u32x2*)(wp + 32);
                u32x4 B = (u32x4){ wlo.x, wlo.y, whi.x, whi.y };
                u32x4 A0 = (u32x4){ xk[0][2 * c2].x, xk[0][2 * c2].y,
                                    xk[0][2 * c2 + 1].x, xk[0][2 * c2 + 1].y };
                u32x4 A1 = (u32x4){ xk[1][2 * c2].x, xk[1][2 * c2].y,
                                    xk[1][2 * c2 + 1].x, xk[1][2 * c2 + 1].y };
                D0 = mfma32(A0, B, D0);
                D1 = mfma32(A1, B, D1);
            }
            *(u32x2*)(sm + vt_off(16 * ot + h, 32 * w + 4 * g)) =
                (u32x2){ bf16pk(D0.x, D0.y), bf16pk(D0.z, D0.w) };
            *(u32x2*)(sm + vt_off(16 * ot + h, 32 * w + 16 + 4 * g)) =
                (u32x2){ bf16pk(D1.x, D1.y), bf16pk(D1.z, D1.w) };
        }
    }

    // ---- phase C: Y-frags for both q-tiles (Mt from global/L2) ----
    u32x2 yf[8][2];   // yf[jt][qt]: lane h = Y[q=q0+16qt+h][b=16jt+4g+i]
    {
        u32x2 bx[2][8];
#pragma unroll
        for (int qt = 0; qt < 2; ++qt)
#pragma unroll
            for (int c = 0; c < 8; ++c)
                bx[qt][c] = *(const u32x2*)(sm + ks_off(q0 + 16 * qt + h, 16 * c + 4 * g));
#pragma unroll
        for (int jt = 0; jt < 8; ++jt) {
            f32x4 a0 = Z, a1 = Z;
#pragma unroll
            for (int c2 = 0; c2 < 4; ++c2) {
                const char* mp = wsb + ((h + 16 * jt) << 8) + ((32 * c2 + 4 * g) << 1);
                u32x2 mlo = *(const u32x2*)mp;
                u32x2 mhi = *(const u32x2*)(mp + 32);
                u32x4 A = (u32x4){ mlo.x, mlo.y, mhi.x, mhi.y };
                u32x4 B0 = (u32x4){ bx[0][2 * c2].x, bx[0][2 * c2].y,
                                    bx[0][2 * c2 + 1].x, bx[0][2 * c2 + 1].y };
                u32x4 B1 = (u32x4){ bx[1][2 * c2].x, bx[1][2 * c2].y,
                                    bx[1][2 * c2 + 1].x, bx[1][2 * c2 + 1].y };
                a0 = mfma32(A, B0, a0);
                a1 = mfma32(A, B1, a1);
            }
            yf[jt][0] = (u32x2){ bf16pk(a0.x, a0.y), bf16pk(a0.z, a0.w) };
            yf[jt][1] = (u32x2){ bf16pk(a1.x, a1.y), bf16pk(a1.z, a1.w) };
        }
    }
    __syncthreads();   // Vt visible

    // ---- main loop: S^T = Xs*yf ; P = exp(S+v) (B-frag-ready) ; O^T += Vt*P ----
    f32x4 Oacc[8][2];  // Oacc[ot][qt]: lane h reg r = O^T[o=16ot+4g+r][q=q0+16qt+h]
#pragma unroll
    for (int ot = 0; ot < 8; ++ot) { Oacc[ot][0] = Z; Oacc[ot][1] = Z; }
    float ls0 = 0.f, ls1 = 0.f;

#pragma unroll 2
    for (int kc2 = 0; kc2 < 8; ++kc2) {
        u32x2 pk0[2], pk1[2];
#pragma unroll
        for (int kk = 0; kk < 2; ++kk) {
            const int kc = 2 * kc2 + kk;
            f32x4 a0 = Z, a1 = Z;
#pragma unroll
            for (int c2 = 0; c2 < 4; ++c2) {
                u32x2 xlo = *(const u32x2*)(sm + ks_off(16 * kc + h, 32 * c2 + 4 * g));
                u32x2 xhi = *(const u32x2*)(sm + ks_off(16 * kc + h, 32 * c2 + 16 + 4 * g));
                u32x4 A = (u32x4){ xlo.x, xlo.y, xhi.x, xhi.y };
                u32x4 B0 = (u32x4){ yf[2 * c2][0].x, yf[2 * c2][0].y,
                                    yf[2 * c2 + 1][0].x, yf[2 * c2 + 1][0].y };
                u32x4 B1 = (u32x4){ yf[2 * c2][1].x, yf[2 * c2][1].y,
                                    yf[2 * c2 + 1][1].x, yf[2 * c2 + 1][1].y };
                a0 = mfma32(A, B0, a0);   // lane h reg r = S[k=16kc+4g+r][q=q0+h]
                a1 = mfma32(A, B1, a1);   // ... q=q0+16+h
            }
            f32x4 vv = *(const f32x4*)(sm + VOFF + (16 * kc + 4 * g) * 4);
            float e0 = __expf(a0.x + vv.x), e1 = __expf(a0.y + vv.y);
            float e2 = __expf(a0.z + vv.z), e3 = __expf(a0.w + vv.w);
            float f0 = __expf(a1.x + vv.x), f1 = __expf(a1.y + vv.y);
            float f2 = __expf(a1.z + vv.z), f3 = __expf(a1.w + vv.w);
            ls0 += e0 + e1 + e2 + e3;
            ls1 += f0 + f1 + f2 + f3;
            pk0[kk] = (u32x2){ bf16pk(e0, e1), bf16pk(e2, e3) };
            pk1[kk] = (u32x2){ bf16pk(f0, f1), bf16pk(f2, f3) };
        }
        u32x4 pa0 = (u32x4){ pk0[0].x, pk0[0].y, pk0[1].x, pk0[1].y };
        u32x4 pa1 = (u32x4){ pk1[0].x, pk1[0].y, pk1[1].x, pk1[1].y };
#pragma unroll
        for (int ot = 0; ot < 8; ++ot) {
            u32x2 vlo = *(const u32x2*)(sm + vt_off(16 * ot + h, 32 * kc2 + 4 * g));
            u32x2 vhi = *(const u32x2*)(sm + vt_off(16 * ot + h, 32 * kc2 + 16 + 4 * g));
            u32x4 A = (u32x4){ vlo.x, vlo.y, vhi.x, vhi.y };
            Oacc[ot][0] = mfma32(A, pa0, Oacc[ot][0]);
            Oacc[ot][1] = mfma32(A, pa1, Oacc[ot][1]);
        }
    }
    ls0 += __shfl_xor(ls0, 16); ls0 += __shfl_xor(ls0, 32);
    ls1 += __shfl_xor(ls1, 16); ls1 += __shfl_xor(ls1, 32);
    const float li0 = 1.0f / ls0;   // for q = q0 + h
    const float li1 = 1.0f / ls1;   // for q = q0 + 16 + h

    // ---- epilogue: O^T is store-ready (regs r = 4 contiguous o-cols) ----
#pragma unroll
    for (int ot = 0; ot < 8; ++ot) {
        f32x4 bvv = *(const f32x4*)(bv + 16 * ot + 4 * g);
        f32x4 r0, r1;
#pragma unroll
        for (int j = 0; j < 4; ++j) {
            r0[j] = Oacc[ot][0][j] * li0 + bvv[j];
            r1[j] = Oacc[ot][1][j] * li1 + bvv[j];
        }
        *(f32x4*)(out + (size_t)(R0 + q0 + h) * 128 + 16 * ot + 4 * g)      = r0;
        *(f32x4*)(out + (size_t)(R0 + q0 + 16 + h) * 128 + 16 * ot + 4 * g) = r1;
    }
}

extern "C" void kernel_launch(void* const* d_in, const int* in_sizes, int n_in,
                              void* d_out, int out_size, void* d_ws, size_t ws_size,
                              hipStream_t stream) {
    const float* x  = (const float*)d_in[0];
    const float* Wq = (const float*)d_in[2];
    const float* bq = (const float*)d_in[3];
    const float* Wk = (const float*)d_in[4];
    const float* Wv = (const float*)d_in[6];
    const float* bv = (const float*)d_in[7];
    float* out = (float*)d_out;
    char* wsb = (char*)d_ws;

    hipFuncSetAttribute((const void*)sattn,
                        hipFuncAttributeMaxDynamicSharedMemorySize, LDSSZ);

    sattn_pre<<<dim3(129), dim3(256), 0, stream>>>(Wq, bq, Wk, Wv, wsb);
    sattn<<<dim3(512), dim3(512), LDSSZ, stream>>>(x, bv, wsb, out);
}